// Round 10
// baseline (58.950 us; speedup 1.0000x reference)
//
#include <hip/hip_runtime.h>
#include <hip/hip_fp16.h>

typedef _Float16 half8  __attribute__((ext_vector_type(8)));
typedef _Float16 half4  __attribute__((ext_vector_type(4)));
typedef _Float16 h2v    __attribute__((ext_vector_type(2)));
typedef __fp16   fp16x2 __attribute__((ext_vector_type(2)));
typedef float    f32x4  __attribute__((ext_vector_type(4)));

#define B_N     2048
#define KLTOT   2048
#define NCHUNK  128
#define CHUNK_ROWS 16      // B_N / NCHUNK
#define NREP    3          // DIAGNOSTIC: repeat mlp work 3x (idempotent) to surface counters

// ---- workspace layout (dword slots) ----
#define WS_PART  0                         // 128*2048*2 = 524288
#define WS_W2F   (WS_PART + 524288)        // 2048*256 uints (f16-packed A-frags)
#define WS_W1H   (WS_W2F + 524288)         // 2048*16 uints (f16 pairs)
#define WS_B1H   (WS_W1H + 32768)          // 2048*16 uints
#define WS_W3H   (WS_B1H + 32768)          // 2048*8 uints (f16 pairs, j padded to 16)
#define WS_B2P   (WS_W3H + 16384)          // 2048*16 f32

// 5/5/4/4 h-slot packing: k-slot s = g*8+e maps to hidden unit hmap(g,e)
__device__ __forceinline__ int hmap(int g, int e) {
    return (g < 2) ? ((e < 5) ? g * 5 + e : -1)
                   : ((e < 4) ? 10 + (g - 2) * 4 + e : -1);
}

__device__ __forceinline__ unsigned int f16b(float f) {
    union { _Float16 h; unsigned short u; } c;
    c.h = (_Float16)f;
    return (unsigned int)c.u;
}

// ---------------- stats: partial sums over batch chunks ----------------
__global__ __launch_bounds__(256) void stats_partial(const float* __restrict__ x,
                                                     float* __restrict__ part) {
    int c4 = blockIdx.x * 256 + threadIdx.x;          // 0..511
    int chunk = blockIdx.y;                           // 0..127
    const float4* p = (const float4*)(x + (size_t)(chunk * CHUNK_ROWS) * KLTOT) + c4;
    float4 s = {0.f, 0.f, 0.f, 0.f}, s2 = {0.f, 0.f, 0.f, 0.f};
#pragma unroll
    for (int r = 0; r < CHUNK_ROWS; ++r) {
        float4 v = p[(size_t)r * (KLTOT / 4)];
        s.x += v.x; s.y += v.y; s.z += v.z; s.w += v.w;
        s2.x = fmaf(v.x, v.x, s2.x); s2.y = fmaf(v.y, v.y, s2.y);
        s2.z = fmaf(v.z, v.z, s2.z); s2.w = fmaf(v.w, v.w, s2.w);
    }
    float4* o = (float4*)(part + ((size_t)chunk * KLTOT + (size_t)c4 * 4) * 2);
    float4 o0 = {s.x, s2.x, s.y, s2.y};
    float4 o1 = {s.z, s2.z, s.w, s2.w};
    o[0] = o0;
    o[1] = o1;
}

// ---------------- prep: finalize stats + pack f16 weights (32 cols/block) ----------------
__global__ __launch_bounds__(256) void prep_w(
    const float* __restrict__ part,
    const float* __restrict__ W1, const float* __restrict__ b1,
    const float* __restrict__ W2, const float* __restrict__ b2,
    const float* __restrict__ W3,
    unsigned int* __restrict__ W2f,
    unsigned int* __restrict__ W1h, unsigned int* __restrict__ b1h,
    unsigned int* __restrict__ W3h, float* __restrict__ b2p)
{
    __shared__ float sW2[32 * 216];       // 27.6 KB
    __shared__ float red[256][2];
    __shared__ float smu[32], srs[32];
    const int tid = threadIdx.x;
    const int col0 = blockIdx.x * 32;

    {
        const float4* src = (const float4*)(W2 + (size_t)col0 * 216);
        for (int t = tid; t < 32 * 54; t += 256)
            ((float4*)sW2)[t] = src[t];
    }

    {
        const int col_l = tid & 31, cg = tid >> 5;    // 8 chunk-groups of 16
        const float2* pp = (const float2*)part;
        float s = 0.f, s2 = 0.f;
#pragma unroll 4
        for (int i = 0; i < 16; ++i) {
            float2 v = pp[(size_t)(cg * 16 + i) * KLTOT + col0 + col_l];
            s += v.x; s2 += v.y;
        }
        red[tid][0] = s; red[tid][1] = s2;
    }
    __syncthreads();

    if (tid < 32) {
        float S = 0.f, S2 = 0.f;
#pragma unroll
        for (int k = 0; k < 8; ++k) {
            S  += red[tid + 32 * k][0];
            S2 += red[tid + 32 * k][1];
        }
        float mu  = S / (float)B_N;
        float var = fmaxf(S2 / (float)B_N - mu * mu, 0.f);
        smu[tid] = mu;
        srs[tid] = 1.f / (sqrtf(var) + 1e-8f);
    }

#pragma unroll 1
    for (int i = 0; i < 32; ++i) {
        int t = i * 256 + tid;
        int col = t >> 8, d = t & 255;
        unsigned int u[2];
#pragma unroll
        for (int h = 0; h < 2; ++h) {
            int idx = d * 2 + h;
            int gg = idx >> 7, j = (idx >> 3) & 15, e = idx & 7;
            int hh = hmap(gg, e);
            float v = (hh >= 0 && j < 12) ? sW2[col * 216 + hh * 12 + j] : 0.f;
            u[h] = f16b(v);
        }
        W2f[(size_t)(col0 + col) * 256 + d] = u[0] | (u[1] << 16);
    }
    __syncthreads();

#pragma unroll
    for (int i = 0; i < 2; ++i) {
        int t = i * 256 + tid;
        int col = t >> 4, l = t & 15;
        int gg = l >> 2, q = l & 3;
        unsigned int wu = 0, bu = 0;
        if (q < 3) {
            float mu = smu[col], rs = srs[col];
            float w0 = 0.f, b0 = 0.f, w1v = 0.f, b1v = 0.f;
            int h0 = hmap(gg, q * 2), h1_ = hmap(gg, q * 2 + 1);
            if (h0 >= 0) {
                w0 = W1[(size_t)(col0 + col) * 18 + h0] * rs;
                b0 = fmaf(-mu, w0, b1[(size_t)(col0 + col) * 18 + h0]);
            }
            if (h1_ >= 0) {
                w1v = W1[(size_t)(col0 + col) * 18 + h1_] * rs;
                b1v = fmaf(-mu, w1v, b1[(size_t)(col0 + col) * 18 + h1_]);
            }
            wu = f16b(w0) | (f16b(w1v) << 16);
            bu = f16b(b0) | (f16b(b1v) << 16);
        }
        W1h[(size_t)(col0 + col) * 16 + l] = wu;
        b1h[(size_t)(col0 + col) * 16 + l] = bu;
    }
    {
        int col = tid >> 3, l = tid & 7;
        int j0 = 2 * l, j1 = 2 * l + 1;
        float v0 = (j0 < 12) ? W3[(size_t)(col0 + col) * 12 + j0] : 0.f;
        float v1 = (j1 < 12) ? W3[(size_t)(col0 + col) * 12 + j1] : 0.f;
        W3h[(size_t)(col0 + col) * 8 + l] = f16b(v0) | (f16b(v1) << 16);
    }
#pragma unroll
    for (int i = 0; i < 2; ++i) {
        int t = i * 256 + tid;
        int col = t >> 4, l = t & 15;
        b2p[(size_t)(col0 + col) * 16 + l] =
            (l < 12) ? b2[(size_t)(col0 + col) * 12 + l] : 0.f;
    }
}

// ---------------- main kernel: R7 structure + NREP diagnostic repeat ----------------
#define LJS 18           // lj stride (dwords)
#define CSC 292          // col stride (16*18 + 4 pad)

__global__ __launch_bounds__(512, 4) void mlp_mfma(
    const float* __restrict__ x,
    const unsigned int* __restrict__ W2f,
    const unsigned int* __restrict__ W1h, const unsigned int* __restrict__ b1h,
    const unsigned int* __restrict__ W3h, const float* __restrict__ b2p,
    const float* __restrict__ b3,
    float* __restrict__ out)
{
    __shared__ float tile[16 * CSC];      // 18.7 KB: [col][lj][rc]
    const int tid = threadIdx.x;
    const int kl0 = blockIdx.x * 16;
    const int b0  = blockIdx.y * 256;

#pragma unroll 1
    for (int rep = 0; rep < NREP; ++rep) {
        // ---- stage x [256 rows][16 cols] -> tile[c][r&15][r>>4] ----
#pragma unroll
        for (int p = 0; p < 2; ++p) {
            int idx = p * 512 + tid;
            int c4 = idx & 3, r = idx >> 2;
            f32x4 v = *(const f32x4*)(x + (size_t)(b0 + r) * KLTOT + kl0 + c4 * 4);
            int base = (r & 15) * LJS + (r >> 4);
#pragma unroll
            for (int e = 0; e < 4; ++e)
                tile[(c4 * 4 + e) * CSC + base] = v[e];
        }
        __syncthreads();

        const int w = tid >> 6, l = tid & 63;
        const int g = l >> 4, lj = l & 15;
        const h2v z2 = {(_Float16)0.f, (_Float16)0.f};
        const f32x4 zc = {0.f, 0.f, 0.f, 0.f};

        const int colA = kl0 + w, colB = kl0 + w + 8;

        union { uint4 u; half8 h; } afA, afB;
        afA.u = ((const uint4*)W2f)[(size_t)colA * 64 + g * 16 + lj];
        afB.u = ((const uint4*)W2f)[(size_t)colB * 64 + g * 16 + lj];
        union { uint4 u; h2v p[4]; } w1A, b1A, w1B, b1B;
        w1A.u = ((const uint4*)W1h)[(size_t)colA * 4 + g];
        w1B.u = ((const uint4*)W1h)[(size_t)colB * 4 + g];
        b1A.u = ((const uint4*)b1h)[(size_t)colA * 4 + g];
        b1B.u = ((const uint4*)b1h)[(size_t)colB * 4 + g];
        union { uint2 u; half4 h; } a2A, a2B;
        a2A.u = ((const uint2*)W3h)[(size_t)colA * 4 + g];
        a2B.u = ((const uint2*)W3h)[(size_t)colB * 4 + g];
        f32x4 b2A = ((const f32x4*)b2p)[(size_t)colA * 4 + g];
        f32x4 b2B = ((const f32x4*)b2p)[(size_t)colB * 4 + g];
        float b3A = b3[colA], b3B = b3[colB];

#define COLPASS(CLOC, AF, W1U, B1U, A2, B2R, B3V)                                   \
        {                                                                           \
            const float* xb = &tile[(CLOC) * CSC + lj * LJS];                       \
            float2 xv[8];                                                           \
            _Pragma("unroll")                                                       \
            for (int q = 0; q < 8; ++q) xv[q] = *(const float2*)(xb + 2 * q);       \
            float res[4];                                                           \
            _Pragma("unroll")                                                       \
            for (int rb = 0; rb < 16; ++rb) {                                       \
                float xsv = (rb & 1) ? xv[rb >> 1].y : xv[rb >> 1].x;               \
                _Float16 xh = (_Float16)xsv;                                        \
                h2v x2 = {xh, xh};                                                  \
                union { h2v p[4]; half8 h; } bf;                                    \
                bf.p[0] = __builtin_elementwise_max(x2 * W1U.p[0] + B1U.p[0], z2);  \
                bf.p[1] = __builtin_elementwise_max(x2 * W1U.p[1] + B1U.p[1], z2);  \
                bf.p[2] = __builtin_elementwise_max(x2 * W1U.p[2] + B1U.p[2], z2);  \
                bf.p[3] = z2;                                                       \
                f32x4 acc = __builtin_amdgcn_mfma_f32_16x16x32_f16(AF.h, bf.h, B2R, 0, 0, 0); \
                union { fp16x2 c[2]; half4 h; } zf;                                 \
                zf.c[0] = __builtin_amdgcn_cvt_pkrtz(fmaxf(acc[0], 0.f), fmaxf(acc[1], 0.f)); \
                zf.c[1] = __builtin_amdgcn_cvt_pkrtz(fmaxf(acc[2], 0.f), fmaxf(acc[3], 0.f)); \
                f32x4 acc2 = __builtin_amdgcn_mfma_f32_16x16x16f16(A2.h, zf.h, zc, 0, 0, 0); \
                if ((rb >> 2) == g) res[rb & 3] = acc2[0] + B3V;                    \
            }                                                                       \
            float* tb = &tile[(CLOC) * CSC + lj * LJS + g * 4];                     \
            float2 r01 = {res[0], res[1]}, r23 = {res[2], res[3]};                  \
            *(float2*)tb = r01;                                                     \
            *(float2*)(tb + 2) = r23;                                               \
        }

        COLPASS(w,     afA, w1A, b1A, a2A, b2A, b3A)
        COLPASS(w + 8, afB, w1B, b1B, a2B, b2B, b3B)
#undef COLPASS

        __syncthreads();

        // ---- coalesced store: out[r][c] from tile[c][r&15][r>>4] ----
#pragma unroll
        for (int p = 0; p < 2; ++p) {
            int idx = p * 512 + tid;
            int c4 = idx & 3, r = idx >> 2;
            int base = (r & 15) * LJS + (r >> 4);
            f32x4 v;
#pragma unroll
            for (int e = 0; e < 4; ++e)
                v[e] = tile[(c4 * 4 + e) * CSC + base];
            *(f32x4*)(out + (size_t)(b0 + r) * KLTOT + kl0 + c4 * 4) = v;
        }
        __syncthreads();
        asm volatile("" ::: "memory");   // force full re-execution each rep
    }
}

extern "C" void kernel_launch(void* const* d_in, const int* in_sizes, int n_in,
                              void* d_out, int out_size, void* d_ws, size_t ws_size,
                              hipStream_t stream) {
    const float* x  = (const float*)d_in[0];
    const float* W1 = (const float*)d_in[1];
    const float* b1 = (const float*)d_in[2];
    const float* W2 = (const float*)d_in[3];
    const float* b2 = (const float*)d_in[4];
    const float* W3 = (const float*)d_in[5];
    const float* b3 = (const float*)d_in[6];
    float* out = (float*)d_out;

    float* ws = (float*)d_ws;
    float*        part = ws + WS_PART;
    unsigned int* W2f  = (unsigned int*)(ws + WS_W2F);
    unsigned int* W1h  = (unsigned int*)(ws + WS_W1H);
    unsigned int* b1h  = (unsigned int*)(ws + WS_B1H);
    unsigned int* W3h  = (unsigned int*)(ws + WS_W3H);
    float*        b2p  = ws + WS_B2P;

    stats_partial<<<dim3(2, NCHUNK),           256, 0, stream>>>(x, part);
    prep_w       <<<dim3(KLTOT / 32),          256, 0, stream>>>(part, W1, b1, W2, b2, W3,
                                                                 W2f, W1h, b1h, W3h, b2p);
    mlp_mfma     <<<dim3(KLTOT / 16, B_N / 256), 512, 0, stream>>>(
        x, W2f, W1h, b1h, W3h, b2p, b3, out);
}

// Round 12
// 30.922 us; speedup vs baseline: 1.9064x; 1.9064x over previous
//
#include <hip/hip_runtime.h>
#include <hip/hip_fp16.h>

typedef _Float16 half8  __attribute__((ext_vector_type(8)));
typedef _Float16 half4  __attribute__((ext_vector_type(4)));
typedef _Float16 h2v    __attribute__((ext_vector_type(2)));
typedef __fp16   fp16x2 __attribute__((ext_vector_type(2)));
typedef float    f32x4  __attribute__((ext_vector_type(4)));

#define B_N    2048
#define KLTOT  2048
#define NCHUNK 128
#define CHUNK_ROWS 16     // B_N / NCHUNK
#define XCS    580        // xt col stride (dwords): %32==4, %4==0
#define LJS2   36         // xt lj stride: %32==4, %4==0

// 5/5/4/4 h-slot packing
__device__ __forceinline__ int hmap(int g, int e) {
    return (g < 2) ? ((e < 5) ? g * 5 + e : -1)
                   : ((e < 4) ? 10 + (g - 2) * 4 + e : -1);
}

__device__ __forceinline__ unsigned int f16b(float f) {
    union { _Float16 h; unsigned short u; } c;
    c.h = (_Float16)f;
    return (unsigned int)c.u;
}

// ---------------- kernel 1: stats partials (proven R7 code) ----------------
__global__ __launch_bounds__(256) void stats_partial(const float* __restrict__ x,
                                                     float* __restrict__ part) {
    int c4 = blockIdx.x * 256 + threadIdx.x;          // 0..511
    int chunk = blockIdx.y;                           // 0..127
    const float4* p = (const float4*)(x + (size_t)(chunk * CHUNK_ROWS) * KLTOT) + c4;
    float4 s = {0.f, 0.f, 0.f, 0.f}, s2 = {0.f, 0.f, 0.f, 0.f};
#pragma unroll
    for (int r = 0; r < CHUNK_ROWS; ++r) {
        float4 v = p[(size_t)r * (KLTOT / 4)];
        s.x += v.x; s.y += v.y; s.z += v.z; s.w += v.w;
        s2.x = fmaf(v.x, v.x, s2.x); s2.y = fmaf(v.y, v.y, s2.y);
        s2.z = fmaf(v.z, v.z, s2.z); s2.w = fmaf(v.w, v.w, s2.w);
    }
    float4* o = (float4*)(part + ((size_t)chunk * KLTOT + (size_t)c4 * 4) * 2);
    float4 o0 = {s.x, s2.x, s.y, s2.y};
    float4 o1 = {s.z, s2.z, s.w, s2.w};
    o[0] = o0;
    o[1] = o1;
}

// ---------------- kernel 2: fused finalize + prep + MLP ----------------
// 512 blocks x 512 thr (2/CU). Block = 16 cols x 512 rows.
__global__ __launch_bounds__(512, 4) void fused_main(
    const float* __restrict__ x,
    const float* __restrict__ part,
    const float* __restrict__ W1, const float* __restrict__ b1,
    const float* __restrict__ W2, const float* __restrict__ b2,
    const float* __restrict__ W3, const float* __restrict__ b3,
    float* __restrict__ out)
{
    __shared__ float        xt[16 * XCS];        // 37.1 KB  [col][lj*36 + rc]
    __shared__ unsigned int afb[16 * 256];       // 16 KB    W2tmp then A-frags
    __shared__ float        red[512][2];         // 4 KB     stats partial-reduce
    __shared__ unsigned int w1h[16][16], b1h[16][16], w3h[16][8];
    __shared__ float        b2f[16][16], smu[16], srs[16], sb3v[16];

    const int tid = threadIdx.x;
    // XCD-chunked swizzle (512 blocks, 8 XCDs, 64/chunk; bijective: 512%8==0)
    const int bid = blockIdx.x;
    const int nf  = (bid & 7) * 64 + (bid >> 3);
    const int cgp = nf & 127, rg = nf >> 7;
    const int cols0 = cgp * 16, rows0 = rg * 512;

    // ---- S1: stats finalize partials (L2-hit) + stage x tile ----
    {
        const int c = tid & 15, q = tid >> 4;      // q: 0..31
        float s = 0.f, s2 = 0.f;
#pragma unroll
        for (int m = 0; m < 4; ++m) {
            float2 v = *(const float2*)&part[((size_t)(q + 32 * m) * KLTOT + cols0 + c) * 2];
            s += v.x; s2 += v.y;
        }
        red[tid][0] = s; red[tid][1] = s2;
    }
    {
        const int c = tid & 15, rr = tid >> 4;     // rr: 16-row group (0..31)
#pragma unroll
        for (int i = 0; i < 16; ++i) {
            int r = rr * 16 + i;
            xt[c * XCS + i * LJS2 + rr] = x[(size_t)(rows0 + r) * KLTOT + cols0 + c];
        }
    }
    __syncthreads();

    // ---- S2: finish stats; stage W2 into afb (as float W2tmp) ----
    if (tid < 16) {
        float S = 0.f, S2 = 0.f;
#pragma unroll 8
        for (int m = 0; m < 32; ++m) {
            S  += red[tid + 16 * m][0];
            S2 += red[tid + 16 * m][1];
        }
        float mu  = S / (float)B_N;
        float var = fmaxf(S2 / (float)B_N - mu * mu, 0.f);
        smu[tid]  = mu;
        srs[tid]  = 1.f / (sqrtf(var) + 1e-8f);
        sb3v[tid] = b3[cols0 + tid];
    }
    {
        float* W2tmp = (float*)afb;
        const float4* src = (const float4*)(W2 + (size_t)cols0 * 216);
        for (int i = tid; i < 864; i += 512)
            ((float4*)W2tmp)[i] = src[i];
    }
    __syncthreads();

    // ---- S3: read W2tmp -> regs (frag pack); write small tables ----
    unsigned int dw[8];
    {
        const float* W2tmp = (const float*)afb;
        const int col = tid >> 5, d0 = (tid & 31) * 8;
#pragma unroll
        for (int k = 0; k < 8; ++k) {
            int d = d0 + k;
            unsigned int u[2];
#pragma unroll
            for (int h = 0; h < 2; ++h) {
                int idx = d * 2 + h;
                int gg = idx >> 7, j = (idx >> 3) & 15, e = idx & 7;
                int hh = hmap(gg, e);
                float v = (hh >= 0 && j < 12) ? W2tmp[col * 216 + hh * 12 + j] : 0.f;
                u[h] = f16b(v);
            }
            dw[k] = u[0] | (u[1] << 16);
        }
    }
    if (tid < 256) {
        int c2 = tid >> 4, l = tid & 15;
        int gg = l >> 2, q = l & 3;
        unsigned int wu = 0, bu = 0;
        if (q < 3) {
            float mu = smu[c2], rs = srs[c2];
            float w0 = 0.f, b0 = 0.f, w1v = 0.f, b1v = 0.f;
            int h0 = hmap(gg, q * 2), h1_ = hmap(gg, q * 2 + 1);
            if (h0 >= 0) {
                w0 = W1[(size_t)(cols0 + c2) * 18 + h0] * rs;
                b0 = fmaf(-mu, w0, b1[(size_t)(cols0 + c2) * 18 + h0]);
            }
            if (h1_ >= 0) {
                w1v = W1[(size_t)(cols0 + c2) * 18 + h1_] * rs;
                b1v = fmaf(-mu, w1v, b1[(size_t)(cols0 + c2) * 18 + h1_]);
            }
            wu = f16b(w0) | (f16b(w1v) << 16);
            bu = f16b(b0) | (f16b(b1v) << 16);
        }
        w1h[c2][l] = wu;
        b1h[c2][l] = bu;
        b2f[c2][l] = (l < 12) ? b2[(size_t)(cols0 + c2) * 12 + l] : 0.f;
    } else if (tid < 384) {
        int t2 = tid - 256;
        int c2 = t2 >> 3, l = t2 & 7;
        int j0 = 2 * l, j1 = 2 * l + 1;
        float v0 = (j0 < 12) ? W3[(size_t)(cols0 + c2) * 12 + j0] : 0.f;
        float v1 = (j1 < 12) ? W3[(size_t)(cols0 + c2) * 12 + j1] : 0.f;
        w3h[c2][l] = f16b(v0) | (f16b(v1) << 16);
    }
    __syncthreads();

    // ---- S4: write A-frags over W2tmp ----
    {
        const int col = tid >> 5, d0 = (tid & 31) * 8;
#pragma unroll
        for (int k = 0; k < 8; ++k)
            afb[col * 256 + d0 + k] = dw[k];
    }
    __syncthreads();

    // ---- Phase C: dual chained MFMA (R7-proven math), 2 cols/wave, 32 rb/col ----
    const int w = tid >> 6, l = tid & 63;
    const int g = l >> 4, lj = l & 15;
    const h2v z2 = {(_Float16)0.f, (_Float16)0.f};
    const f32x4 zc = {0.f, 0.f, 0.f, 0.f};

#pragma unroll
    for (int half = 0; half < 2; ++half) {
        const int cl = w + half * 8;

        union { uint4 u; half8 h; } af;
        af.u = *(const uint4*)&afb[cl * 256 + (g * 16 + lj) * 4];
        union { uint4 u; h2v p[4]; } w1u, b1u;
        w1u.u = *(const uint4*)&w1h[cl][g * 4];
        b1u.u = *(const uint4*)&b1h[cl][g * 4];
        union { uint2 u; half4 h; } a2;
        a2.u = *(const uint2*)&w3h[cl][g * 2];
        f32x4 b2r = *(const f32x4*)&b2f[cl][g * 4];
        float b3v = sb3v[cl];

        float res[8];
        const float* xb = &xt[cl * XCS + lj * LJS2];
#pragma unroll
        for (int rbq = 0; rbq < 4; ++rbq) {
            f32x4 xa = *(const f32x4*)(xb + rbq * 8);
            f32x4 xc = *(const f32x4*)(xb + rbq * 8 + 4);
#pragma unroll
            for (int k = 0; k < 8; ++k) {
                float xsv = (k < 4) ? xa[k & 3] : xc[k & 3];
                _Float16 xh = (_Float16)xsv;
                h2v x2 = {xh, xh};
                union { h2v p[4]; half8 h; } bf;
                bf.p[0] = __builtin_elementwise_max(x2 * w1u.p[0] + b1u.p[0], z2);
                bf.p[1] = __builtin_elementwise_max(x2 * w1u.p[1] + b1u.p[1], z2);
                bf.p[2] = __builtin_elementwise_max(x2 * w1u.p[2] + b1u.p[2], z2);
                bf.p[3] = z2;

                f32x4 acc = __builtin_amdgcn_mfma_f32_16x16x32_f16(af.h, bf.h, b2r, 0, 0, 0);

                union { fp16x2 c[2]; half4 h; } zf;
                zf.c[0] = __builtin_amdgcn_cvt_pkrtz(fmaxf(acc[0], 0.f), fmaxf(acc[1], 0.f));
                zf.c[1] = __builtin_amdgcn_cvt_pkrtz(fmaxf(acc[2], 0.f), fmaxf(acc[3], 0.f));

                f32x4 acc2 = __builtin_amdgcn_mfma_f32_16x16x16f16(a2.h, zf.h, zc, 0, 0, 0);

                if (rbq == g) res[k] = acc2[0] + b3v;   // lane rows: (g*8+k)*16 + lj
            }
        }
        float* tb = &xt[cl * XCS + lj * LJS2 + g * 8];
        f32x4 r0 = { res[0], res[1], res[2], res[3] };
        f32x4 r1 = { res[4], res[5], res[6], res[7] };
        *(f32x4*)tb = r0;
        *(f32x4*)(tb + 4) = r1;
    }
    __syncthreads();

    // ---- store: out[r][c] from xt ----
#pragma unroll
    for (int p = 0; p < 4; ++p) {
        int idx = p * 512 + tid;
        int c4 = idx & 3, r = idx >> 2;
        int base = (r & 15) * LJS2 + (r >> 4);
        f32x4 v;
#pragma unroll
        for (int e = 0; e < 4; ++e)
            v[e] = xt[(c4 * 4 + e) * XCS + base];
        *(f32x4*)(out + (size_t)(rows0 + r) * KLTOT + cols0 + c4 * 4) = v;
    }
}

extern "C" void kernel_launch(void* const* d_in, const int* in_sizes, int n_in,
                              void* d_out, int out_size, void* d_ws, size_t ws_size,
                              hipStream_t stream) {
    const float* x  = (const float*)d_in[0];
    const float* W1 = (const float*)d_in[1];
    const float* b1 = (const float*)d_in[2];
    const float* W2 = (const float*)d_in[3];
    const float* b2 = (const float*)d_in[4];
    const float* W3 = (const float*)d_in[5];
    const float* b3 = (const float*)d_in[6];
    float* out  = (float*)d_out;
    float* part = (float*)d_ws;     // 128 * 2048 * 2 floats = 2 MB

    stats_partial<<<dim3(2, NCHUNK), 256, 0, stream>>>(x, part);
    fused_main   <<<dim3(512),       512, 0, stream>>>(x, part, W1, b1, W2, b2, W3, b3, out);
}